// Round 19
// baseline (150.952 us; speedup 1.0000x reference)
//
#include <hip/hip_runtime.h>
#include <hip/hip_bf16.h>

typedef unsigned short u16;
typedef short short8 __attribute__((ext_vector_type(8)));
typedef short short4v __attribute__((ext_vector_type(4)));
typedef float floatx4 __attribute__((ext_vector_type(4)));
typedef float float16v __attribute__((ext_vector_type(16)));

#define NNODES 2048
#define BATCH  64
#define DIN    64
#define DOUT   64
#define EMB    16

__device__ __forceinline__ u16 f2bf(float f) {
  union { float f; unsigned u; } v; v.f = f;
  unsigned r = v.u + 0x7fffu + ((v.u >> 16) & 1u);
  return (u16)(r >> 16);
}

__device__ __forceinline__ void gload_lds16(const void* g, void* l) {
  __builtin_amdgcn_global_load_lds(
      (const __attribute__((address_space(1))) void*)g,
      (__attribute__((address_space(3))) void*)l, 16, 0, 0);
}

// ---------------------------------------------------------------------------
// Fused prologue (R16 configuration).
//   blocks [0,768):     wgen (native layout)  -> Wall
//   blocks [768,2816):  adj_softmax row n     -> Sb
//   blocks [2816,4864): trans_x tile          -> xtt
// ---------------------------------------------------------------------------
__global__ __launch_bounds__(256) void prologue(const float* __restrict__ E,
                                                const float* __restrict__ pool,
                                                const float* __restrict__ x,
                                                u16* __restrict__ Sb,
                                                u16* __restrict__ xtt,
                                                u16* __restrict__ W) {
  int bid = blockIdx.x;
  int t = threadIdx.x;

  if (bid < 768) {
    // ---- weight generation, native (k,i,o) order, E via s_load_dwordx16 ----
    int ec = bid % 48, nc = bid / 48;
    int e = ec * 256 + t;            // e' = k*4096 + i*64 + o
    int n0 = nc * 128;
    float pv[16];
#pragma unroll
    for (int d = 0; d < 16; d++) {
      float p = pool[(size_t)d * 12288 + e];
      if (e < 4096) p -= pool[(size_t)d * 12288 + 8192 + e];
      if (e >= 8192) p += p;
      pv[d] = p;
    }
#pragma unroll
    for (int d = 0; d < 16; d++) asm volatile("" : "+v"(pv[d]));  // pin
    const float16v* er16 = (const float16v*)(E + (size_t)n0 * EMB);
#pragma unroll 4
    for (int nn = 0; nn < 128; nn += 2) {
      float16v ev0 = er16[nn];
      float16v ev1 = er16[nn + 1];
      float a0 = 0.0f, a1 = 0.0f;
#pragma unroll
      for (int d = 0; d < 16; d++) {
        a0 = fmaf(ev0[d], pv[d], a0);
        a1 = fmaf(ev1[d], pv[d], a1);
      }
      W[(size_t)(n0 + nn) * 12288 + e] = f2bf(a0);
      W[(size_t)(n0 + nn + 1) * 12288 + e] = f2bf(a1);
    }

  } else if (bid < 2816) {
    // ---- S = softmax(relu(E E^T)) row n, bf16 out ----
    int n = bid - 768;
    const float4* ep = (const float4*)(E + (size_t)n * EMB);
    float4 e0 = ep[0], e1 = ep[1], e2 = ep[2], e3 = ep[3];
    float lg[8];
    float mx = 0.0f;  // relu => all logits >= 0
#pragma unroll
    for (int j = 0; j < 8; j++) {
      int m = t + j * 256;
      const float4* mp = (const float4*)(E + (size_t)m * EMB);
      float4 a = mp[0], b = mp[1], c = mp[2], d = mp[3];
      float dot = e0.x * a.x + e0.y * a.y + e0.z * a.z + e0.w * a.w
                + e1.x * b.x + e1.y * b.y + e1.z * b.z + e1.w * b.w
                + e2.x * c.x + e2.y * c.y + e2.z * c.z + e2.w * c.w
                + e3.x * d.x + e3.y * d.y + e3.z * d.z + e3.w * d.w;
      dot = fmaxf(dot, 0.0f);
      lg[j] = dot;
      mx = fmaxf(mx, dot);
    }
    __shared__ float smax[4], ssum[4];
#pragma unroll
    for (int off = 32; off > 0; off >>= 1) mx = fmaxf(mx, __shfl_xor(mx, off, 64));
    if ((t & 63) == 0) smax[t >> 6] = mx;
    __syncthreads();
    mx = fmaxf(fmaxf(smax[0], smax[1]), fmaxf(smax[2], smax[3]));
    float sum = 0.0f;
#pragma unroll
    for (int j = 0; j < 8; j++) {
      float e = __expf(lg[j] - mx);
      lg[j] = e;
      sum += e;
    }
#pragma unroll
    for (int off = 32; off > 0; off >>= 1) sum += __shfl_xor(sum, off, 64);
    if ((t & 63) == 0) ssum[t >> 6] = sum;
    __syncthreads();
    sum = ssum[0] + ssum[1] + ssum[2] + ssum[3];
    float inv = 1.0f / sum;
#pragma unroll
    for (int j = 0; j < 8; j++)
      Sb[(size_t)n * NNODES + t + j * 256] = f2bf(lg[j] * inv);

  } else {
    // ---- x (B,N,DIN) f32 -> xtt (B*64+c, N) bf16 ----
    __shared__ float tile[64][69];
    int u = bid - 2816;
    int b = u >> 5;
    int m0 = (u & 31) * 64;
    int r = t >> 2, cs = (t & 3) * 16;
    const float* xp = x + ((size_t)b * NNODES + m0 + r) * DIN + cs;
    float4 v0 = ((const float4*)xp)[0];
    float4 v1 = ((const float4*)xp)[1];
    float4 v2 = ((const float4*)xp)[2];
    float4 v3 = ((const float4*)xp)[3];
    *(float4*)&tile[r][cs]      = v0;
    *(float4*)&tile[r][cs + 4]  = v1;
    *(float4*)&tile[r][cs + 8]  = v2;
    *(float4*)&tile[r][cs + 12] = v3;
    __syncthreads();
    int c = t >> 2, ms = (t & 3) * 16;
    short8 o0, o1;
#pragma unroll
    for (int j = 0; j < 8; j++) o0[j] = (short)f2bf(tile[ms + j][c]);
#pragma unroll
    for (int j = 0; j < 8; j++) o1[j] = (short)f2bf(tile[ms + 8 + j][c]);
    u16* op = xtt + ((size_t)b * 64 + c) * NNODES + m0 + ms;
    *(short8*)op = o0;
    *(short8*)(op + 8) = o1;
  }
}

// ---------------------------------------------------------------------------
// Deep-pipelined bf16 GEMM, R19: BK=32 for 2 BLOCKS/CU.
// C(2048 x 4096) = A(2048 x 2048) * Bt(4096 x 2048)^T.
// BM=256, BN=128, BK=32. 512 threads = 8 waves (4M x 2N, 64x64 each).
// 3 LDS buffers = 72 KB -> TWO blocks co-resident per CU: independent blocks
// cover each other's barrier drains (m114 cross-block overlap - distinct
// from R10's intra-block waves, which stall together at every barrier).
// Stage t+2, counted vmcnt(3) (= own stage size), ONE barrier per tile,
// XOR swizzle slot^(row&3) on both global source and ds_read (rule #21).
// NT=64 tiles; per-tile = 8 ds_read_b128 + 16 MFMA per wave.
// ---------------------------------------------------------------------------
#define GK 2048      // K
#define GN 4096      // output cols
#define NT 64        // K / 32
#define BUFU 12288   // u16 per buffer: A 256*32=8192 + B 128*32=4096

#define GEMM_PREAMBLE                                                          \
  __shared__ u16 smem[3 * BUFU];  /* 73728 B */                                \
  int t = threadIdx.x, lane = t & 63, wave = t >> 6;                           \
  int lin = blockIdx.y * gridDim.x + blockIdx.x;                               \
  int nwg = gridDim.x * gridDim.y;                                             \
  int sw = (lin & 7) * (nwg >> 3) + (lin >> 3);                                \
  int bx = sw & 31, by = sw >> 5;                                              \
  int m0 = by * 256, n0 = bx * 128;                                            \
  const u16* pg[3];                                                            \
  int lof[3];                                                                  \
  _Pragma("unroll") for (int j = 0; j < 2; j++) {                              \
    int c = t + 512 * j;                                                       \
    int row = c >> 2;                                                          \
    int gs = (c & 3) ^ (row & 3);                                              \
    pg[j] = A + (size_t)(m0 + row) * GK + gs * 8;                              \
    lof[j] = c * 8;                                                            \
  }                                                                            \
  {                                                                            \
    int c = t;                                                                 \
    int row = c >> 2;                                                          \
    int gs = (c & 3) ^ (row & 3);                                              \
    pg[2] = Bt + (size_t)(n0 + row) * GK + gs * 8;                             \
    lof[2] = 8192 + c * 8;                                                     \
  }                                                                            \
  auto stage = [&](int b, int kt) {                                            \
    _Pragma("unroll") for (int j = 0; j < 3; j++)                              \
        gload_lds16(pg[j] + kt, &smem[b * BUFU + lof[j]]);                     \
  };                                                                           \
  int wr = wave >> 1, wc = wave & 1;                                           \
  int lr = lane & 15, lg = lane >> 4;                                          \
  floatx4 acc[4][4];                                                           \
  _Pragma("unroll") for (int mi = 0; mi < 4; mi++)                             \
      _Pragma("unroll") for (int ni = 0; ni < 4; ni++)                         \
          acc[mi][ni] = (floatx4)0.0f;                                         \
  int aoff[4], boff[4];                                                        \
  _Pragma("unroll") for (int mi = 0; mi < 4; mi++) {                           \
    int row = wr * 64 + mi * 16 + lr;                                          \
    aoff[mi] = row * 32 + (lg ^ (row & 3)) * 8;                                \
  }                                                                            \
  _Pragma("unroll") for (int ni = 0; ni < 4; ni++) {                           \
    int row = wc * 64 + ni * 16 + lr;                                          \
    boff[ni] = 8192 + row * 32 + (lg ^ (row & 3)) * 8;                         \
  }                                                                            \
  auto compute = [&](int b) {                                                  \
    const u16* base = &smem[b * BUFU];                                         \
    short8 af[4], bf[4];                                                       \
    _Pragma("unroll") for (int mi = 0; mi < 4; mi++)                           \
        af[mi] = *(const short8*)(base + aoff[mi]);                            \
    _Pragma("unroll") for (int ni = 0; ni < 4; ni++)                           \
        bf[ni] = *(const short8*)(base + boff[ni]);                            \
    _Pragma("unroll") for (int mi = 0; mi < 4; mi++)                           \
        _Pragma("unroll") for (int ni = 0; ni < 4; ni++)                       \
            acc[mi][ni] = __builtin_amdgcn_mfma_f32_16x16x32_bf16(             \
                af[mi], bf[ni], acc[mi][ni], 0, 0, 0);                         \
  };                                                                           \
  stage(0, 0);                                                                 \
  stage(1, 32);                                                                \
  for (int tt = 0; tt < NT - 2; ++tt) {                                        \
    asm volatile("s_waitcnt vmcnt(3)" ::: "memory");                           \
    __builtin_amdgcn_s_barrier();                                              \
    stage((tt + 2) % 3, (tt + 2) * 32);                                        \
    compute(tt % 3);                                                           \
  }                                                                            \
  asm volatile("s_waitcnt vmcnt(3)" ::: "memory");                             \
  __builtin_amdgcn_s_barrier();                                                \
  compute((NT - 2) % 3);                                                       \
  asm volatile("s_waitcnt vmcnt(0)" ::: "memory");                             \
  __builtin_amdgcn_s_barrier();                                                \
  compute((NT - 1) % 3);                                                       \
  _Pragma("unroll") for (int mi = 0; mi < 4; mi++)                             \
      _Pragma("unroll") for (int ni = 0; ni < 4; ni++) {                       \
    int row = m0 + wr * 64 + mi * 16 + lg * 4;                                 \
    int col = n0 + wc * 64 + ni * 16 + lr;                                     \
    _Pragma("unroll") for (int r = 0; r < 4; r++)                              \
        C[(size_t)(row + r) * GN + col] = f2bf(acc[mi][ni][r]);                \
  }

__global__ __launch_bounds__(512) void gemm_plain(const u16* __restrict__ A,
                                                  const u16* __restrict__ Bt,
                                                  u16* __restrict__ C) {
  GEMM_PREAMBLE
}

__global__ __launch_bounds__(512) void gemm_tr(const u16* __restrict__ A,
                                               const u16* __restrict__ Bt,
                                               u16* __restrict__ C,
                                               u16* __restrict__ Ct) {
  GEMM_PREAMBLE
  // ---- transposed epilogue: Ct[col][row], per-wave stride-72 LDS scratch ----
  __syncthreads();  // all waves done reading the pipeline buffers
  u16* scr = smem + wave * 4608;  // 8 waves * 4608 u16 = 36864 u16 = 72 KB ✓
#pragma unroll
  for (int mi = 0; mi < 4; mi++)
#pragma unroll
    for (int ni = 0; ni < 4; ni++) {
      int ncol = ni * 16 + lr;
      int chunk = mi * 2 + (lg >> 1);
      int off = ncol * 72 + chunk * 8 + (lg & 1) * 4;
      short4v sv;
#pragma unroll
      for (int r = 0; r < 4; r++) sv[r] = (short)f2bf(acc[mi][ni][r]);
      *(short4v*)&scr[off] = sv;
    }
  int c = lane;
  u16* op = Ct + (size_t)(n0 + wc * 64 + c) * GK + m0 + wr * 64;
#pragma unroll
  for (int jj = 0; jj < 8; jj++) {
    short8 v = *(const short8*)&scr[c * 72 + jj * 8];
    *(short8*)(op + jj * 8) = v;
  }
}

// ---------------------------------------------------------------------------
// Final per-node fused GEMM: out[b,n,o] = sum_kk A[b,kk]*Weff[n,kk,o] + bias[n,o]
// W native node-major [kk][o]; staged into swizzled [o][slot] LDS layout.
// ---------------------------------------------------------------------------
__global__ __launch_bounds__(256) void final_k(const float* __restrict__ x,
                                               const float* __restrict__ E,
                                               const float* __restrict__ bpool,
                                               const u16* __restrict__ xg1,
                                               const u16* __restrict__ xg2,
                                               const u16* __restrict__ W,
                                               float* __restrict__ out) {
  __shared__ u16 Xs[3][64][72];   // [k][b][i], +8 pad: 2-way banks only
  __shared__ u16 Ws[64 * 200];    // [o][swizzled kk]
  __shared__ float bias_s[64];
  int n = blockIdx.x, t = threadIdx.x;

  {  // stage k=0 slab from fp32 x
    int b = t >> 2, i0 = (t & 3) * 16;
    const float* xp = x + ((size_t)b * NNODES + n) * DIN + i0;
    float4 v0 = ((const float4*)xp)[0];
    float4 v1 = ((const float4*)xp)[1];
    float4 v2 = ((const float4*)xp)[2];
    float4 v3 = ((const float4*)xp)[3];
    u16* d = &Xs[0][b][i0];
    d[0] = f2bf(v0.x); d[1] = f2bf(v0.y); d[2] = f2bf(v0.z); d[3] = f2bf(v0.w);
    d[4] = f2bf(v1.x); d[5] = f2bf(v1.y); d[6] = f2bf(v1.z); d[7] = f2bf(v1.w);
    d[8] = f2bf(v2.x); d[9] = f2bf(v2.y); d[10] = f2bf(v2.z); d[11] = f2bf(v2.w);
    d[12] = f2bf(v3.x); d[13] = f2bf(v3.y); d[14] = f2bf(v3.z); d[15] = f2bf(v3.w);
  }
  for (int idx = t; idx < 512; idx += 256) {  // k=1,2 slabs (rows of xg1/xg2)
    short8 v1 = *(const short8*)(xg1 + (size_t)n * 4096 + idx * 8);
    *(short8*)&Xs[1][idx >> 3][(idx & 7) * 8] = v1;
    short8 v2 = *(const short8*)(xg2 + (size_t)n * 4096 + idx * 8);
    *(short8*)&Xs[2][idx >> 3][(idx & 7) * 8] = v2;
  }
  for (int idx = t; idx < 1536; idx += 256) {  // W: native [kk][o] -> swizzled
    short8 v = *(const short8*)(W + (size_t)n * 12288 + idx * 8);
    int kk = idx >> 3;
    int oo = (idx & 7) * 8;
    int c8 = kk >> 3, k7 = kk & 7;
#pragma unroll
    for (int j = 0; j < 8; j++) {
      int o = oo + j;
      Ws[o * 200 + ((c8 ^ (o >> 3)) << 3) + k7] = (u16)v[j];
    }
  }
  if (t < 64) {
    float acc = 0.0f;
#pragma unroll
    for (int d = 0; d < 16; d++)
      acc = fmaf(E[(size_t)n * EMB + d], bpool[d * 64 + t], acc);
    bias_s[t] = acc;
  }
  __syncthreads();

  int lane = t & 63, wave = t >> 6;
  int lr = lane & 15, lg = lane >> 4;
  int wb = wave * 16;
  floatx4 acc[4];
#pragma unroll
  for (int ot = 0; ot < 4; ot++) acc[ot] = (floatx4)0.0f;

#pragma unroll
  for (int ks = 0; ks < 6; ks++) {
    int kk = ks * 32 + lg * 8;           // multiple of 8
    int c8 = ks * 4 + lg;                // kk >> 3
    short8 a = *(const short8*)&Xs[kk >> 6][wb + lr][kk & 63];
#pragma unroll
    for (int ot = 0; ot < 4; ot++) {
      int o = ot * 16 + lr;
      short8 bb = *(const short8*)&Ws[o * 200 + ((c8 ^ (o >> 3)) << 3)];
      acc[ot] = __builtin_amdgcn_mfma_f32_16x16x32_bf16(a, bb, acc[ot], 0, 0, 0);
    }
  }
#pragma unroll
  for (int ot = 0; ot < 4; ot++) {
    int o = ot * 16 + lr;
    float bs = bias_s[o];
#pragma unroll
    for (int r = 0; r < 4; r++) {
      int b = wb + lg * 4 + r;
      out[((size_t)b * NNODES + n) * DOUT + o] = acc[ot][r] + bs;
    }
  }
}

// ---------------------------------------------------------------------------
extern "C" void kernel_launch(void* const* d_in, const int* in_sizes, int n_in,
                              void* d_out, int out_size, void* d_ws, size_t ws_size,
                              hipStream_t stream) {
  const float* x     = (const float*)d_in[0];  // (64,2048,64)
  const float* E     = (const float*)d_in[1];  // (2048,16)
  const float* pool  = (const float*)d_in[2];  // (16,3,64,64)
  const float* bpool = (const float*)d_in[3];  // (16,64)
  float* out = (float*)d_out;

  char* ws = (char*)d_ws;
  u16* Sb   = (u16*)(ws);                    // 2048*2048*2  = 8 MiB
  u16* xtt  = (u16*)(ws + 8388608);          // 4096*2048*2  = 16 MiB
  u16* xg1  = (u16*)(ws + 25165824);         // 2048*4096*2
  u16* xg1t = (u16*)(ws + 41943040);         // 4096*2048*2
  u16* xg2  = (u16*)(ws + 58720256);         // 2048*4096*2
  u16* Wall = (u16*)(ws + 75497472);         // 2048*12288*2 = 48 MiB  (end 120 MiB)

  // fused: wgen (768, s_load_dwordx16 + paired chains) + softmax + trans_x
  prologue<<<4864, 256, 0, stream>>>(E, pool, x, Sb, xtt, Wall);
  // xg1[n][b*64+c] = sum_m S[n][m] * x[b][m][c]; also emits xg1t = xg1^T
  gemm_tr<<<dim3(32, 8), 512, 0, stream>>>(Sb, xtt, xg1, xg1t);
  // xg2[n][bc] = sum_m S[n][m] * xg1[m][bc]   (un-scaled; T2 folded into Weff)
  gemm_plain<<<dim3(32, 8), 512, 0, stream>>>(Sb, xg1t, xg2);
  final_k<<<NNODES, 256, 0, stream>>>(x, E, bpool, xg1, xg2, Wall, out);
}

// Round 20
// 142.118 us; speedup vs baseline: 1.0622x; 1.0622x over previous
//
#include <hip/hip_runtime.h>
#include <hip/hip_bf16.h>

typedef unsigned short u16;
typedef short short8 __attribute__((ext_vector_type(8)));
typedef short short4v __attribute__((ext_vector_type(4)));
typedef float floatx4 __attribute__((ext_vector_type(4)));
typedef float float16v __attribute__((ext_vector_type(16)));

#define NNODES 2048
#define BATCH  64
#define DIN    64
#define DOUT   64
#define EMB    16

__device__ __forceinline__ u16 f2bf(float f) {
  union { float f; unsigned u; } v; v.f = f;
  unsigned r = v.u + 0x7fffu + ((v.u >> 16) & 1u);
  return (u16)(r >> 16);
}

__device__ __forceinline__ void gload_lds16(const void* g, void* l) {
  __builtin_amdgcn_global_load_lds(
      (const __attribute__((address_space(1))) void*)g,
      (__attribute__((address_space(3))) void*)l, 16, 0, 0);
}

// ---------------------------------------------------------------------------
// Fused prologue (R16/R18 configuration - best measured, 142.8 us total).
//   blocks [0,768):     wgen (native layout)  -> Wall   (heaviest: first)
//   blocks [768,2816):  adj_softmax row n     -> Sb
//   blocks [2816,4864): trans_x tile          -> xtt
// wgen: E row via single s_load_dwordx16; TWO nodes/iter with independent
// FMA chains; pv pinned via asm "+v".
// ---------------------------------------------------------------------------
__global__ __launch_bounds__(256) void prologue(const float* __restrict__ E,
                                                const float* __restrict__ pool,
                                                const float* __restrict__ x,
                                                u16* __restrict__ Sb,
                                                u16* __restrict__ xtt,
                                                u16* __restrict__ W) {
  int bid = blockIdx.x;
  int t = threadIdx.x;

  if (bid < 768) {
    // ---- weight generation, native (k,i,o) order, E via s_load_dwordx16 ----
    int ec = bid % 48, nc = bid / 48;
    int e = ec * 256 + t;            // e' = k*4096 + i*64 + o
    int n0 = nc * 128;
    float pv[16];
#pragma unroll
    for (int d = 0; d < 16; d++) {
      float p = pool[(size_t)d * 12288 + e];
      if (e < 4096) p -= pool[(size_t)d * 12288 + 8192 + e];
      if (e >= 8192) p += p;
      pv[d] = p;
    }
#pragma unroll
    for (int d = 0; d < 16; d++) asm volatile("" : "+v"(pv[d]));  // pin
    const float16v* er16 = (const float16v*)(E + (size_t)n0 * EMB);
#pragma unroll 4
    for (int nn = 0; nn < 128; nn += 2) {
      float16v ev0 = er16[nn];
      float16v ev1 = er16[nn + 1];
      float a0 = 0.0f, a1 = 0.0f;
#pragma unroll
      for (int d = 0; d < 16; d++) {
        a0 = fmaf(ev0[d], pv[d], a0);
        a1 = fmaf(ev1[d], pv[d], a1);
      }
      W[(size_t)(n0 + nn) * 12288 + e] = f2bf(a0);
      W[(size_t)(n0 + nn + 1) * 12288 + e] = f2bf(a1);
    }

  } else if (bid < 2816) {
    // ---- S = softmax(relu(E E^T)) row n, bf16 out ----
    int n = bid - 768;
    const float4* ep = (const float4*)(E + (size_t)n * EMB);
    float4 e0 = ep[0], e1 = ep[1], e2 = ep[2], e3 = ep[3];
    float lg[8];
    float mx = 0.0f;  // relu => all logits >= 0
#pragma unroll
    for (int j = 0; j < 8; j++) {
      int m = t + j * 256;
      const float4* mp = (const float4*)(E + (size_t)m * EMB);
      float4 a = mp[0], b = mp[1], c = mp[2], d = mp[3];
      float dot = e0.x * a.x + e0.y * a.y + e0.z * a.z + e0.w * a.w
                + e1.x * b.x + e1.y * b.y + e1.z * b.z + e1.w * b.w
                + e2.x * c.x + e2.y * c.y + e2.z * c.z + e2.w * c.w
                + e3.x * d.x + e3.y * d.y + e3.z * d.z + e3.w * d.w;
      dot = fmaxf(dot, 0.0f);
      lg[j] = dot;
      mx = fmaxf(mx, dot);
    }
    __shared__ float smax[4], ssum[4];
#pragma unroll
    for (int off = 32; off > 0; off >>= 1) mx = fmaxf(mx, __shfl_xor(mx, off, 64));
    if ((t & 63) == 0) smax[t >> 6] = mx;
    __syncthreads();
    mx = fmaxf(fmaxf(smax[0], smax[1]), fmaxf(smax[2], smax[3]));
    float sum = 0.0f;
#pragma unroll
    for (int j = 0; j < 8; j++) {
      float e = __expf(lg[j] - mx);
      lg[j] = e;
      sum += e;
    }
#pragma unroll
    for (int off = 32; off > 0; off >>= 1) sum += __shfl_xor(sum, off, 64);
    if ((t & 63) == 0) ssum[t >> 6] = sum;
    __syncthreads();
    sum = ssum[0] + ssum[1] + ssum[2] + ssum[3];
    float inv = 1.0f / sum;
#pragma unroll
    for (int j = 0; j < 8; j++)
      Sb[(size_t)n * NNODES + t + j * 256] = f2bf(lg[j] * inv);

  } else {
    // ---- x (B,N,DIN) f32 -> xtt (B*64+c, N) bf16 ----
    // stride 69: read-phase banks {c, c+16, c, c+16} per 4-lane group -> 2-way
    __shared__ float tile[64][69];
    int u = bid - 2816;
    int b = u >> 5;
    int m0 = (u & 31) * 64;
    int r = t >> 2, cs = (t & 3) * 16;
    const float* xp = x + ((size_t)b * NNODES + m0 + r) * DIN + cs;
    float4 v0 = ((const float4*)xp)[0];
    float4 v1 = ((const float4*)xp)[1];
    float4 v2 = ((const float4*)xp)[2];
    float4 v3 = ((const float4*)xp)[3];
    *(float4*)&tile[r][cs]      = v0;
    *(float4*)&tile[r][cs + 4]  = v1;
    *(float4*)&tile[r][cs + 8]  = v2;
    *(float4*)&tile[r][cs + 12] = v3;
    __syncthreads();
    int c = t >> 2, ms = (t & 3) * 16;
    short8 o0, o1;
#pragma unroll
    for (int j = 0; j < 8; j++) o0[j] = (short)f2bf(tile[ms + j][c]);
#pragma unroll
    for (int j = 0; j < 8; j++) o1[j] = (short)f2bf(tile[ms + 8 + j][c]);
    u16* op = xtt + ((size_t)b * 64 + c) * NNODES + m0 + ms;
    *(short8*)op = o0;
    *(short8*)(op + 8) = o1;
  }
}

// ---------------------------------------------------------------------------
// Deep-pipelined bf16 GEMM (R8 config - BEST measured: plain ~39, tr 44.4 us):
// C(2048 x 4096) = A(2048 x 2048) * Bt(4096 x 2048)^T.
// BM=256, BN=128, BK=64. 512 threads = 8 waves (4M x 2N, 64x64 each).
// 3 LDS buffers, stage t+2, counted vmcnt(6), ONE barrier per tile, XOR
// swizzle slot^(row&7) on both global source and ds_read (rule #21).
// FINAL experiment ledger (all within-harness measured):
//   2-phase split (R4)        44.6 -> 42.8/45 regress
//   m201 phase port (R9)      44.6 -> 49.3 regress
//   4 waves/SIMD (R10)        44.6 -> 44.2 null
//   fat-wave 1/SIMD (R11)     44.6 -> 59.3 regress
//   hidden-wgen waves (R17)   44.6 -> 83.4 regress
//   BK=32 2-blocks/CU (R19)   44.4 -> 47.4 regress (8-way ds_read conflicts)
// -> this lockstep structure is the local optimum at this shape.
// ---------------------------------------------------------------------------
#define GK 2048      // K
#define GN 4096      // output cols
#define NT 32        // K / 64
#define BUFU 24576   // u16 per buffer: A 256*64=16384 + B 128*64=8192

#define GEMM_PREAMBLE                                                          \
  __shared__ u16 smem[3 * BUFU];                                               \
  int t = threadIdx.x, lane = t & 63, wave = t >> 6;                           \
  int lin = blockIdx.y * gridDim.x + blockIdx.x;                               \
  int nwg = gridDim.x * gridDim.y;                                             \
  int sw = (lin & 7) * (nwg >> 3) + (lin >> 3);                                \
  int bx = sw & 31, by = sw >> 5;                                              \
  int m0 = by * 256, n0 = bx * 128;                                            \
  const u16* pg[6];                                                            \
  int lof[6];                                                                  \
  _Pragma("unroll") for (int j = 0; j < 4; j++) {                              \
    int c = t + 512 * j;                                                       \
    int row = c >> 3;                                                          \
    int gs = (c & 7) ^ (row & 7);                                              \
    pg[j] = A + (size_t)(m0 + row) * GK + gs * 8;                              \
    lof[j] = c * 8;                                                            \
  }                                                                            \
  _Pragma("unroll") for (int j = 0; j < 2; j++) {                              \
    int c = t + 512 * j;                                                       \
    int row = c >> 3;                                                          \
    int gs = (c & 7) ^ (row & 7);                                              \
    pg[4 + j] = Bt + (size_t)(n0 + row) * GK + gs * 8;                         \
    lof[4 + j] = 16384 + c * 8;                                                \
  }                                                                            \
  auto stage = [&](int b, int kt) {                                            \
    _Pragma("unroll") for (int j = 0; j < 6; j++)                              \
        gload_lds16(pg[j] + kt, &smem[b * BUFU + lof[j]]);                     \
  };                                                                           \
  int wr = wave >> 1, wc = wave & 1;                                           \
  int lr = lane & 15, lg = lane >> 4;                                          \
  floatx4 acc[4][4];                                                           \
  _Pragma("unroll") for (int mi = 0; mi < 4; mi++)                             \
      _Pragma("unroll") for (int ni = 0; ni < 4; ni++)                         \
          acc[mi][ni] = (floatx4)0.0f;                                         \
  int aoff[2][4], boff[2][4];                                                  \
  _Pragma("unroll") for (int s = 0; s < 2; s++) {                              \
    _Pragma("unroll") for (int mi = 0; mi < 4; mi++) {                         \
      int row = wr * 64 + mi * 16 + lr;                                        \
      int slot = s * 4 + lg;                                                   \
      aoff[s][mi] = row * 64 + (slot ^ (row & 7)) * 8;                         \
    }                                                                          \
    _Pragma("unroll") for (int ni = 0; ni < 4; ni++) {                         \
      int row = wc * 64 + ni * 16 + lr;                                        \
      int slot = s * 4 + lg;                                                   \
      boff[s][ni] = 16384 + row * 64 + (slot ^ (row & 7)) * 8;                 \
    }                                                                          \
  }                                                                            \
  auto compute = [&](int b) {                                                  \
    const u16* base = &smem[b * BUFU];                                         \
    short8 af[2][4], bf[2][4];                                                 \
    _Pragma("unroll") for (int s = 0; s < 2; s++) {                            \
      _Pragma("unroll") for (int mi = 0; mi < 4; mi++)                         \
          af[s][mi] = *(const short8*)(base + aoff[s][mi]);                    \
      _Pragma("unroll") for (int ni = 0; ni < 4; ni++)                         \
          bf[s][ni] = *(const short8*)(base + boff[s][ni]);                    \
    }                                                                          \
    _Pragma("unroll") for (int s = 0; s < 2; s++)                              \
        _Pragma("unroll") for (int mi = 0; mi < 4; mi++)                       \
            _Pragma("unroll") for (int ni = 0; ni < 4; ni++)                   \
                acc[mi][ni] = __builtin_amdgcn_mfma_f32_16x16x32_bf16(         \
                    af[s][mi], bf[s][ni], acc[mi][ni], 0, 0, 0);               \
  };                                                                           \
  stage(0, 0);                                                                 \
  stage(1, 64);                                                                \
  for (int tt = 0; tt < NT - 2; ++tt) {                                        \
    asm volatile("s_waitcnt vmcnt(6)" ::: "memory");                           \
    __builtin_amdgcn_s_barrier();                                              \
    stage((tt + 2) % 3, (tt + 2) * 64);                                        \
    compute(tt % 3);                                                           \
  }                                                                            \
  asm volatile("s_waitcnt vmcnt(6)" ::: "memory");                             \
  __builtin_amdgcn_s_barrier();                                                \
  compute((NT - 2) % 3);                                                       \
  asm volatile("s_waitcnt vmcnt(0)" ::: "memory");                             \
  __builtin_amdgcn_s_barrier();                                                \
  compute((NT - 1) % 3);                                                       \
  _Pragma("unroll") for (int mi = 0; mi < 4; mi++)                             \
      _Pragma("unroll") for (int ni = 0; ni < 4; ni++) {                       \
    int row = m0 + wr * 64 + mi * 16 + lg * 4;                                 \
    int col = n0 + wc * 64 + ni * 16 + lr;                                     \
    _Pragma("unroll") for (int r = 0; r < 4; r++)                              \
        C[(size_t)(row + r) * GN + col] = f2bf(acc[mi][ni][r]);                \
  }

__global__ __launch_bounds__(512) void gemm_plain(const u16* __restrict__ A,
                                                  const u16* __restrict__ Bt,
                                                  u16* __restrict__ C) {
  GEMM_PREAMBLE
}

__global__ __launch_bounds__(512) void gemm_tr(const u16* __restrict__ A,
                                               const u16* __restrict__ Bt,
                                               u16* __restrict__ C,
                                               u16* __restrict__ Ct) {
  GEMM_PREAMBLE
  // ---- transposed epilogue: Ct[col][row], per-wave stride-72 LDS scratch ----
  __syncthreads();  // all waves done reading the pipeline buffers
  u16* scr = smem + wave * 4608;  // 64 rows * 72 u16 = 9216B per wave
#pragma unroll
  for (int mi = 0; mi < 4; mi++)
#pragma unroll
    for (int ni = 0; ni < 4; ni++) {
      int ncol = ni * 16 + lr;
      // mrow = chunk*8 + (lg&1)*4 + r == mi*16 + lg*4 + r
      int chunk = mi * 2 + (lg >> 1);
      int off = ncol * 72 + chunk * 8 + (lg & 1) * 4;
      short4v sv;
#pragma unroll
      for (int r = 0; r < 4; r++) sv[r] = (short)f2bf(acc[mi][ni][r]);
      *(short4v*)&scr[off] = sv;
    }
  int c = lane;
  u16* op = Ct + (size_t)(n0 + wc * 64 + c) * GK + m0 + wr * 64;
#pragma unroll
  for (int jj = 0; jj < 8; jj++) {
    short8 v = *(const short8*)&scr[c * 72 + jj * 8];
    *(short8*)(op + jj * 8) = v;
  }
}

// ---------------------------------------------------------------------------
// Final per-node fused GEMM: out[b,n,o] = sum_kk A[b,kk]*Weff[n,kk,o] + bias[n,o]
// W arrives in native node-major [kk][o] order (kk = k*64+i); staged into a
// swizzled [o][slot] LDS layout: element (kk,o) at Ws[o*200 + ((kk>>3)^(o>>3))*8
// + (kk&7)].
// ---------------------------------------------------------------------------
__global__ __launch_bounds__(256) void final_k(const float* __restrict__ x,
                                               const float* __restrict__ E,
                                               const float* __restrict__ bpool,
                                               const u16* __restrict__ xg1,
                                               const u16* __restrict__ xg2,
                                               const u16* __restrict__ W,
                                               float* __restrict__ out) {
  __shared__ u16 Xs[3][64][72];   // [k][b][i], +8 pad: 2-way banks only
  __shared__ u16 Ws[64 * 200];    // [o][swizzled kk], see header comment
  __shared__ float bias_s[64];
  int n = blockIdx.x, t = threadIdx.x;

  {  // stage k=0 slab from fp32 x
    int b = t >> 2, i0 = (t & 3) * 16;
    const float* xp = x + ((size_t)b * NNODES + n) * DIN + i0;
    float4 v0 = ((const float4*)xp)[0];
    float4 v1 = ((const float4*)xp)[1];
    float4 v2 = ((const float4*)xp)[2];
    float4 v3 = ((const float4*)xp)[3];
    u16* d = &Xs[0][b][i0];
    d[0] = f2bf(v0.x); d[1] = f2bf(v0.y); d[2] = f2bf(v0.z); d[3] = f2bf(v0.w);
    d[4] = f2bf(v1.x); d[5] = f2bf(v1.y); d[6] = f2bf(v1.z); d[7] = f2bf(v1.w);
    d[8] = f2bf(v2.x); d[9] = f2bf(v2.y); d[10] = f2bf(v2.z); d[11] = f2bf(v2.w);
    d[12] = f2bf(v3.x); d[13] = f2bf(v3.y); d[14] = f2bf(v3.z); d[15] = f2bf(v3.w);
  }
  for (int idx = t; idx < 512; idx += 256) {  // k=1,2 slabs (rows of xg1/xg2)
    short8 v1 = *(const short8*)(xg1 + (size_t)n * 4096 + idx * 8);
    *(short8*)&Xs[1][idx >> 3][(idx & 7) * 8] = v1;
    short8 v2 = *(const short8*)(xg2 + (size_t)n * 4096 + idx * 8);
    *(short8*)&Xs[2][idx >> 3][(idx & 7) * 8] = v2;
  }
  for (int idx = t; idx < 1536; idx += 256) {  // W: native [kk][o] -> swizzled
    short8 v = *(const short8*)(W + (size_t)n * 12288 + idx * 8);
    int kk = idx >> 3;           // e' = idx*8 + j = kk*64 + (oo + j)
    int oo = (idx & 7) * 8;
    int c8 = kk >> 3, k7 = kk & 7;
#pragma unroll
    for (int j = 0; j < 8; j++) {
      int o = oo + j;
      Ws[o * 200 + ((c8 ^ (o >> 3)) << 3) + k7] = (u16)v[j];
    }
  }
  if (t < 64) {
    float acc = 0.0f;
#pragma unroll
    for (int d = 0; d < 16; d++)
      acc = fmaf(E[(size_t)n * EMB + d], bpool[d * 64 + t], acc);
    bias_s[t] = acc;
  }
  __syncthreads();

  int lane = t & 63, wave = t >> 6;
  int lr = lane & 15, lg = lane >> 4;
  int wb = wave * 16;
  floatx4 acc[4];
#pragma unroll
  for (int ot = 0; ot < 4; ot++) acc[ot] = (floatx4)0.0f;

#pragma unroll
  for (int ks = 0; ks < 6; ks++) {
    int kk = ks * 32 + lg * 8;           // multiple of 8
    int c8 = ks * 4 + lg;                // kk >> 3
    short8 a = *(const short8*)&Xs[kk >> 6][wb + lr][kk & 63];
#pragma unroll
    for (int ot = 0; ot < 4; ot++) {
      int o = ot * 16 + lr;
      short8 bb = *(const short8*)&Ws[o * 200 + ((c8 ^ (o >> 3)) << 3)];
      acc[ot] = __builtin_amdgcn_mfma_f32_16x16x32_bf16(a, bb, acc[ot], 0, 0, 0);
    }
  }
#pragma unroll
  for (int ot = 0; ot < 4; ot++) {
    int o = ot * 16 + lr;
    float bs = bias_s[o];
#pragma unroll
    for (int r = 0; r < 4; r++) {
      int b = wb + lg * 4 + r;
      out[((size_t)b * NNODES + n) * DOUT + o] = acc[ot][r] + bs;
    }
  }
}

// ---------------------------------------------------------------------------
extern "C" void kernel_launch(void* const* d_in, const int* in_sizes, int n_in,
                              void* d_out, int out_size, void* d_ws, size_t ws_size,
                              hipStream_t stream) {
  const float* x     = (const float*)d_in[0];  // (64,2048,64)
  const float* E     = (const float*)d_in[1];  // (2048,16)
  const float* pool  = (const float*)d_in[2];  // (16,3,64,64)
  const float* bpool = (const float*)d_in[3];  // (16,64)
  float* out = (float*)d_out;

  char* ws = (char*)d_ws;
  u16* Sb   = (u16*)(ws);                    // 2048*2048*2  = 8 MiB
  u16* xtt  = (u16*)(ws + 8388608);          // 4096*2048*2  = 16 MiB
  u16* xg1  = (u16*)(ws + 25165824);         // 2048*4096*2
  u16* xg1t = (u16*)(ws + 41943040);         // 4096*2048*2
  u16* xg2  = (u16*)(ws + 58720256);         // 2048*4096*2
  u16* Wall = (u16*)(ws + 75497472);         // 2048*12288*2 = 48 MiB  (end 120 MiB)

  // fused: wgen (768, s_load_dwordx16 + paired chains) + softmax + trans_x
  prologue<<<4864, 256, 0, stream>>>(E, pool, x, Sb, xtt, Wall);
  // xg1[n][b*64+c] = sum_m S[n][m] * x[b][m][c]; also emits xg1t = xg1^T
  gemm_tr<<<dim3(32, 8), 512, 0, stream>>>(Sb, xtt, xg1, xg1t);
  // xg2[n][bc] = sum_m S[n][m] * xg1[m][bc]   (un-scaled; T2 folded into Weff)
  gemm_plain<<<dim3(32, 8), 512, 0, stream>>>(Sb, xg1t, xg2);
  final_k<<<NNODES, 256, 0, stream>>>(x, E, bpool, xg1, xg2, Wall, out);
}